// Round 10
// baseline (338.771 us; speedup 1.0000x reference)
//
#include <hip/hip_runtime.h>

typedef short short8 __attribute__((ext_vector_type(8)));
typedef short short4v __attribute__((ext_vector_type(4)));
typedef float f32x4 __attribute__((ext_vector_type(4)));
typedef unsigned short u16;
typedef u16 ushort4v __attribute__((ext_vector_type(4)));

__device__ inline u16 f2bf(float f){
  unsigned int u = __builtin_bit_cast(unsigned int, f);
  u = (u + 0x7fffu + ((u >> 16) & 1u)) >> 16;
  return (u16)u;
}

__device__ inline short8 cat8(short4v a, short4v b){
  short8 r;
  r[0]=a[0]; r[1]=a[1]; r[2]=a[2]; r[3]=a[3];
  r[4]=b[0]; r[5]=b[1]; r[6]=b[2]; r[7]=b[3];
  return r;
}

// async global->LDS, 16B per lane. lds dest = wave-uniform base + lane*16.
__device__ inline void gload_lds16(const void* g, unsigned lds_addr){
  __builtin_amdgcn_global_load_lds((__attribute__((address_space(1))) void*)(uintptr_t)g,
                                   (__attribute__((address_space(3))) void*)(uintptr_t)lds_addr,
                                   16, 0, 0);
}

// ---------------- f32 -> bf16 convert (vectorized) ----------------
__global__ void cvt_bf16(const float* __restrict__ in, u16* __restrict__ out, int n4){
  int stride = gridDim.x * blockDim.x;
  for (int i = blockIdx.x * blockDim.x + threadIdx.x; i < n4; i += stride){
    float4 v = ((const float4*)in)[i];
    ushort4v r = { f2bf(v.x), f2bf(v.y), f2bf(v.z), f2bf(v.w) };
    ((ushort4v*)out)[i] = r;
  }
}

#define BARRIER() { __builtin_amdgcn_sched_barrier(0); __builtin_amdgcn_s_barrier(); __builtin_amdgcn_sched_barrier(0); }
#define VM4() asm volatile("s_waitcnt vmcnt(4)" ::: "memory");

// ================= 256x256 8-phase GEMM (1092 TF/round measured r6) =======
// C[row][NS] output stride NS; grid must be an exact multiple of 256 blocks.
#define MFMA4(MO, AA, BB) { __builtin_amdgcn_s_setprio(1); \
  _Pragma("unroll") for (int m = 0; m < 4; m++) \
    _Pragma("unroll") for (int n = 0; n < 4; n++) \
      acc[(MO)+m][n] = __builtin_amdgcn_mfma_f32_16x16x32_bf16(AA[(MO)+m], BB[n], acc[(MO)+m][n], 0, 0, 0); \
  __builtin_amdgcn_s_setprio(0); }

#define PHASE4(ABASE, BBASE, ST1, ST2, ST3, ST4) { \
    const u16* Ab = (ABASE); const u16* Bb = (BBASE); \
    short8 a0[8], b0[4], a1[8], b1[4]; \
    _Pragma("unroll") for (int m = 0; m < 8; m++){ int row = wm*128 + m*16 + lr; int ph = lg ^ (row & 7); a0[m] = *(const short8*)&Ab[row*64 + ph*8]; } \
    _Pragma("unroll") for (int n = 0; n < 4; n++){ int row = wn*64 + n*16 + lr; int ph = lg ^ (row & 7); b0[n] = *(const short8*)&Bb[row*64 + ph*8]; } \
    ST1 BARRIER() MFMA4(0, a0, b0) BARRIER() \
    _Pragma("unroll") for (int m = 0; m < 8; m++){ int row = wm*128 + m*16 + lr; int ph = (4+lg) ^ (row & 7); a1[m] = *(const short8*)&Ab[row*64 + ph*8]; } \
    _Pragma("unroll") for (int n = 0; n < 4; n++){ int row = wn*64 + n*16 + lr; int ph = (4+lg) ^ (row & 7); b1[n] = *(const short8*)&Bb[row*64 + ph*8]; } \
    ST2 BARRIER() MFMA4(4, a0, b0) BARRIER() \
    ST3 BARRIER() MFMA4(0, a1, b1) BARRIER() \
    ST4 VM4() BARRIER() MFMA4(4, a1, b1) BARRIER() \
  }

template<int OUT_BF16>
__global__ __launch_bounds__(512, 2) void gemm256(const u16* __restrict__ A, const u16* __restrict__ B,
                                                  void* __restrict__ Cv, int M, int NS, int K){
  __shared__ u16 lds[2][32768];
  const int tid = threadIdx.x, wave = tid >> 6, lane = tid & 63;
  const int lr = lane & 15, lg = lane >> 4;
  const int wm = wave >> 2, wn = wave & 3;
  const long bm = blockIdx.x * 256L, bn = blockIdx.y * 256L;
  const int l3 = lane >> 3, l7 = lane & 7;

  const u16* asrc = A + (bm + wave*8 + l3) * (long)K + (l7 ^ l3) * 8;
  const u16* bsrc = B + (bn + wave*8 + l3) * (long)K + (l7 ^ l3) * 8;
  const unsigned ldsbase = (unsigned)(uintptr_t)&lds[0][0];
  const unsigned wdst = wave * 1024u;

#define STG_A(BUF,S,KOFF) gload_lds16(asrc + (size_t)(S)*64*K + (KOFF), ldsbase + (BUF)*65536u + wdst + (S)*8192u);
#define STG_B(BUF,S,KOFF) gload_lds16(bsrc + (size_t)(S)*64*K + (KOFF), ldsbase + (BUF)*65536u + 32768u + wdst + (S)*8192u);

  f32x4 acc[8][4] = {};
  const int nk = K >> 6;          // must be even

  #pragma unroll
  for (int s = 0; s < 4; s++){ STG_A(0, s, 0) }
  #pragma unroll
  for (int s = 0; s < 4; s++){ STG_B(0, s, 0) }
  #pragma unroll
  for (int s = 0; s < 4; s++){ STG_A(1, s, 64) }
  VM4()
  BARRIER()

  for (int i = 0; i < (nk >> 1); i++){
    const size_t kt1 = (size_t)((2*i + 1) << 6);
    const size_t kn0 = (size_t)(((2*i + 2) & (nk - 1)) << 6);
    const size_t kn1 = (size_t)(((2*i + 3) & (nk - 1)) << 6);
    PHASE4(&lds[0][0], &lds[0][16384],
           STG_B(1,0,kt1) STG_B(1,1,kt1),
           STG_B(1,2,kt1) STG_B(1,3,kt1),
           STG_A(0,0,kn0) STG_A(0,1,kn0),
           STG_A(0,2,kn0) STG_A(0,3,kn0))
    PHASE4(&lds[1][0], &lds[1][16384],
           STG_B(0,0,kn0) STG_B(0,1,kn0),
           STG_B(0,2,kn0) STG_B(0,3,kn0),
           STG_A(1,0,kn1) STG_A(1,1,kn1),
           STG_A(1,2,kn1) STG_A(1,3,kn1))
  }
#undef STG_A
#undef STG_B

  #pragma unroll
  for (int m = 0; m < 8; m++){
    #pragma unroll
    for (int n = 0; n < 4; n++){
      #pragma unroll
      for (int r = 0; r < 4; r++){
        long row = bm + wm*128 + m*16 + lg*4 + r;
        long col = bn + wn*64 + n*16 + lr;
        float v = acc[m][n][r];
        if (OUT_BF16) ((u16*)Cv)[row * (long)NS + col] = f2bf(v);
        else          ((float*)Cv)[row * (long)NS + col] = v;
      }
    }
  }
}

// ---------------- 128x128 m97 GEMM (862 TF; NS = output row stride) -------
template<int OUT_BF16>
__global__ __launch_bounds__(256) void gemm_bt(const u16* __restrict__ A, const u16* __restrict__ B,
                                               void* __restrict__ Cv, int M, int NS, int K){
  __shared__ u16 As[128 * 64];
  __shared__ u16 Bs[128 * 64];
  const int tid  = threadIdx.x;
  const int wave = tid >> 6, lane = tid & 63;
  const int lr = lane & 15, lg = lane >> 4;
  const int wm = wave >> 1, wn = wave & 1;
  const long bm = blockIdx.x * 128L, bn = blockIdx.y * 128L;
  const unsigned asb = (unsigned)(uintptr_t)As;
  const unsigned bsb = (unsigned)(uintptr_t)Bs;

  const int  srow = wave * 32 + (lane >> 3);
  const int  scol = ((lane & 7) ^ (lane >> 3)) * 8;
  const u16* aptr = A + (bm + srow) * (long)K + scol;
  const u16* bptr = B + (bn + srow) * (long)K + scol;
  const unsigned sdst = (unsigned)(wave * 4096);

  f32x4 acc[4][4] = {};
  for (int k0 = 0; k0 < K; k0 += 64){
    #pragma unroll
    for (int c = 0; c < 4; c++){
      gload_lds16(aptr + (size_t)(8 * c) * K + k0, asb + sdst + 1024u * c);
      gload_lds16(bptr + (size_t)(8 * c) * K + k0, bsb + sdst + 1024u * c);
    }
    __syncthreads();
    #pragma unroll
    for (int kk = 0; kk < 2; kk++){
      short8 af[4], bfr[4];
      #pragma unroll
      for (int m = 0; m < 4; m++){
        int row = wm * 64 + m * 16 + lr;
        int phys = (kk * 4 + lg) ^ (row & 7);
        af[m] = *(const short8*)&As[row * 64 + phys * 8];
      }
      #pragma unroll
      for (int n = 0; n < 4; n++){
        int row = wn * 64 + n * 16 + lr;
        int phys = (kk * 4 + lg) ^ (row & 7);
        bfr[n] = *(const short8*)&Bs[row * 64 + phys * 8];
      }
      #pragma unroll
      for (int m = 0; m < 4; m++)
        #pragma unroll
        for (int n = 0; n < 4; n++)
          acc[m][n] = __builtin_amdgcn_mfma_f32_16x16x32_bf16(af[m], bfr[n], acc[m][n], 0, 0, 0);
    }
    __syncthreads();
  }
  #pragma unroll
  for (int m = 0; m < 4; m++){
    #pragma unroll
    for (int n = 0; n < 4; n++){
      #pragma unroll
      for (int r = 0; r < 4; r++){
        long row = bm + wm*64 + m*16 + lg*4 + r;
        long col = bn + wn*64 + n*16 + lr;
        float v = acc[m][n][r];
        if (OUT_BF16) ((u16*)Cv)[row * (long)NS + col] = f2bf(v);
        else          ((float*)Cv)[row * (long)NS + col] = v;
      }
    }
  }
}

// ---------------- causal flash attention ----------------
// 256 thr = 4 waves x 16 q-rows. Block (bh, p): heavy H=31-p, light L=p.
// Shared tiles (t<=L) run a FUSED dual-state pass: one K-frag load and one
// V tr-read pipeline feed both states' MFMAs. Grid 32x16 = 512 blocks.
__global__ __launch_bounds__(256, 2) void attn_fwd(const u16* __restrict__ qkv, u16* __restrict__ out){
  const int T = 2048, D3 = 6144, D = 2048, HD = 128;
  const int bh = blockIdx.x;
  const int yy = blockIdx.y;            // 0..15
  const int p = (yy < 8) ? yy : (23 - yy);   // cost-balance dispatch pairs
  const int b = bh >> 4, h = bh & 15;
  const int tid = threadIdx.x, wave = tid >> 6, lane = tid & 63;
  const int lr = lane & 15, lg = lane >> 4;

  __shared__ u16 Klds[64][136];
  __shared__ u16 Vlds[64][136];
  __shared__ u16 Plds[8][16][72];

  const size_t base = (size_t)b * T * D3;
  const unsigned vtr = (unsigned)(uintptr_t)&Vlds[(lane >> 4) * 8 + ((lane >> 2) & 3)][(lane & 3) * 4];

  const int srow = tid >> 4;
  const int scol = (tid & 15) * 8;
  const u16* kgp = qkv + base + (size_t)srow * D3 + D + h * HD + scol;
  const u16* vgp = kgp + D;

  const int H = 31 - p, L = p;
  const int q0A = H * 64 + wave * 16;
  const int q0B = L * 64 + wave * 16;

  short8 qfA[4], qfB[4];
  {
    const u16* qa = qkv + base + (size_t)(q0A + lr) * D3 + h * HD;
    const u16* qb = qkv + base + (size_t)(q0B + lr) * D3 + h * HD;
    #pragma unroll
    for (int kk = 0; kk < 4; kk++){
      qfA[kk] = *(const short8*)(qa + kk*32 + lg*8);
      qfB[kk] = *(const short8*)(qb + kk*32 + lg*8);
    }
  }

  f32x4 oA[8] = {}, oB[8] = {};
  float mA[4], lA[4], mB[4], lB[4];
  #pragma unroll
  for (int r = 0; r < 4; r++){ mA[r] = -1e30f; lA[r] = 0.f; mB[r] = -1e30f; lB[r] = 0.f; }

  const float scale2 = 0.12751971252971732f;  // 1/sqrt(128) * log2(e)
  const float THR = 11.5f;

  // softmax for one state: max-reduce, defer-or-rescale, P-write. No drains.
  #define SMAX(S, MR, LW, O, PSLOT) { \
    float mx[4]; \
    _Pragma("unroll") \
    for (int r = 0; r < 4; r++){ \
      float m0 = fmaxf(fmaxf(S[0][r], S[1][r]), fmaxf(S[2][r], S[3][r])); \
      _Pragma("unroll") \
      for (int msk = 8; msk >= 1; msk >>= 1) m0 = fmaxf(m0, __shfl_xor(m0, msk, 64)); \
      mx[r] = m0; \
    } \
    bool cnd = (mx[0] <= MR[0] + THR) && (mx[1] <= MR[1] + THR) && \
               (mx[2] <= MR[2] + THR) && (mx[3] <= MR[3] + THR); \
    if (__all(cnd)){ \
      _Pragma("unroll") \
      for (int r = 0; r < 4; r++){ \
        float p0 = exp2f(S[0][r] - MR[r]); \
        float p1 = exp2f(S[1][r] - MR[r]); \
        float p2 = exp2f(S[2][r] - MR[r]); \
        float p3 = exp2f(S[3][r] - MR[r]); \
        S[0][r] = p0; S[1][r] = p1; S[2][r] = p2; S[3][r] = p3; \
        float rs = (p0 + p1) + (p2 + p3); \
        _Pragma("unroll") \
        for (int msk = 8; msk >= 1; msk >>= 1) rs += __shfl_xor(rs, msk, 64); \
        LW[r] += rs; \
      } \
    } else { \
      float fsv[4]; \
      _Pragma("unroll") \
      for (int r = 0; r < 4; r++){ \
        float mnew = fmaxf(MR[r], mx[r]); \
        float f = exp2f(MR[r] - mnew); \
        float p0 = exp2f(S[0][r] - mnew); \
        float p1 = exp2f(S[1][r] - mnew); \
        float p2 = exp2f(S[2][r] - mnew); \
        float p3 = exp2f(S[3][r] - mnew); \
        S[0][r] = p0; S[1][r] = p1; S[2][r] = p2; S[3][r] = p3; \
        float rs = (p0 + p1) + (p2 + p3); \
        _Pragma("unroll") \
        for (int msk = 8; msk >= 1; msk >>= 1) rs += __shfl_xor(rs, msk, 64); \
        LW[r] = LW[r] * f + rs; \
        MR[r] = mnew; \
        fsv[r] = f; \
      } \
      _Pragma("unroll") \
      for (int dt = 0; dt < 8; dt++) \
        _Pragma("unroll") \
        for (int r = 0; r < 4; r++) O[dt][r] *= fsv[r]; \
    } \
    _Pragma("unroll") \
    for (int kh = 0; kh < 4; kh++) \
      _Pragma("unroll") \
      for (int r = 0; r < 4; r++) \
        Plds[PSLOT][lg*4 + r][kh*16 + lr] = f2bf(S[kh][r]); \
  }

  #define TR4(VF, BUF, PTR) \
    asm volatile("ds_read_b64_tr_b16 %0, %1"             : "=v"(VF[BUF][0][0]) : "v"(PTR)); \
    asm volatile("ds_read_b64_tr_b16 %0, %1 offset:1088" : "=v"(VF[BUF][0][1]) : "v"(PTR)); \
    asm volatile("ds_read_b64_tr_b16 %0, %1 offset:8704" : "=v"(VF[BUF][1][0]) : "v"(PTR)); \
    asm volatile("ds_read_b64_tr_b16 %0, %1 offset:9792" : "=v"(VF[BUF][1][1]) : "v"(PTR));

  const int ntiles = H + 1;
  short8 kreg[4], vreg[4];
  #pragma unroll
  for (int c = 0; c < 4; c++){
    kreg[c] = *(const short8*)(kgp + (size_t)(16 * c) * D3);
    vreg[c] = *(const short8*)(vgp + (size_t)(16 * c) * D3);
  }

  for (int t = 0; t < ntiles; t++){
    const int k0 = t * 64;
    __syncthreads();
    #pragma unroll
    for (int c = 0; c < 4; c++){
      *(short8*)&Klds[srow + 16*c][scol] = kreg[c];
      *(short8*)&Vlds[srow + 16*c][scol] = vreg[c];
    }
    __syncthreads();
    if (t + 1 < ntiles){
      const u16* kn = kgp + (size_t)(k0 + 64) * D3;
      const u16* vn = vgp + (size_t)(k0 + 64) * D3;
      #pragma unroll
      for (int c = 0; c < 4; c++){
        kreg[c] = *(const short8*)(kn + (size_t)(16 * c) * D3);
        vreg[c] = *(const short8*)(vn + (size_t)(16 * c) * D3);
      }
    }

    if (t <= L){
      // ================= DUAL tile: both states share K frags & V reads ===
      f32x4 sA[4] = {}, sB[4] = {};
      #pragma unroll
      for (int kh = 0; kh < 4; kh++){
        #pragma unroll
        for (int kk = 0; kk < 4; kk++){
          short8 kfrag = *(const short8*)&Klds[kh*16 + lr][kk*32 + lg*8];
          sA[kh] = __builtin_amdgcn_mfma_f32_16x16x32_bf16(qfA[kk], kfrag, sA[kh], 0, 0, 0);
          sB[kh] = __builtin_amdgcn_mfma_f32_16x16x32_bf16(qfB[kk], kfrag, sB[kh], 0, 0, 0);
        }
      }
      // A never needs mask here (k0+63 < q0A since L < H); B masks only at t==L
      const bool maskB = (t == L);
      #pragma unroll
      for (int kh = 0; kh < 4; kh++){
        int key = k0 + kh*16 + lr;
        #pragma unroll
        for (int r = 0; r < 4; r++){
          sA[kh][r] *= scale2;
          float vb = sB[kh][r] * scale2;
          if (maskB && key > q0B + lg*4 + r) vb = -1e30f;
          sB[kh][r] = vb;
        }
      }
      SMAX(sA, mA, lA, oA, wave)
      SMAX(sB, mB, lB, oB, wave + 4)
      asm volatile("s_waitcnt lgkmcnt(0)" ::: "memory");
      __builtin_amdgcn_sched_barrier(0);
      short8 pfA[2], pfB[2];
      #pragma unroll
      for (int k2 = 0; k2 < 2; k2++){
        pfA[k2] = *(const short8*)&Plds[wave][lr][k2*32 + lg*8];
        pfB[k2] = *(const short8*)&Plds[wave + 4][lr][k2*32 + lg*8];
      }
      asm volatile("s_waitcnt lgkmcnt(0)" ::: "memory");
      __builtin_amdgcn_sched_barrier(0);
      short4v vf[2][2][2];
      TR4(vf, 0, vtr)
      #pragma unroll
      for (int dt = 0; dt < 8; dt++){
        if (dt < 7){
          unsigned pn = vtr + (unsigned)((dt + 1) * 32);
          TR4(vf, (dt + 1) & 1, pn)
          asm volatile("s_waitcnt lgkmcnt(4)" ::: "memory");
        } else {
          asm volatile("s_waitcnt lgkmcnt(0)" ::: "memory");
        }
        __builtin_amdgcn_sched_barrier(0);
        short8 v0 = cat8(vf[dt & 1][0][0], vf[dt & 1][0][1]);
        short8 v1 = cat8(vf[dt & 1][1][0], vf[dt & 1][1][1]);
        oA[dt] = __builtin_amdgcn_mfma_f32_16x16x32_bf16(pfA[0], v0, oA[dt], 0, 0, 0);
        oB[dt] = __builtin_amdgcn_mfma_f32_16x16x32_bf16(pfB[0], v0, oB[dt], 0, 0, 0);
        oA[dt] = __builtin_amdgcn_mfma_f32_16x16x32_bf16(pfA[1], v1, oA[dt], 0, 0, 0);
        oB[dt] = __builtin_amdgcn_mfma_f32_16x16x32_bf16(pfB[1], v1, oB[dt], 0, 0, 0);
      }
    } else {
      // ================= heavy-only tile ==================================
      f32x4 sA[4] = {};
      #pragma unroll
      for (int kh = 0; kh < 4; kh++){
        #pragma unroll
        for (int kk = 0; kk < 4; kk++){
          short8 kfrag = *(const short8*)&Klds[kh*16 + lr][kk*32 + lg*8];
          sA[kh] = __builtin_amdgcn_mfma_f32_16x16x32_bf16(qfA[kk], kfrag, sA[kh], 0, 0, 0);
        }
      }
      const bool need_mask = (k0 + 63 > q0A);
      #pragma unroll
      for (int kh = 0; kh < 4; kh++){
        int key = k0 + kh*16 + lr;
        #pragma unroll
        for (int r = 0; r < 4; r++){
          float v = sA[kh][r] * scale2;
          if (need_mask && key > q0A + lg*4 + r) v = -1e30f;
          sA[kh][r] = v;
        }
      }
      SMAX(sA, mA, lA, oA, wave)
      asm volatile("s_waitcnt lgkmcnt(0)" ::: "memory");
      __builtin_amdgcn_sched_barrier(0);
      short8 pf[2];
      #pragma unroll
      for (int k2 = 0; k2 < 2; k2++)
        pf[k2] = *(const short8*)&Plds[wave][lr][k2*32 + lg*8];
      asm volatile("s_waitcnt lgkmcnt(0)" ::: "memory");
      __builtin_amdgcn_sched_barrier(0);
      short4v vf[2][2][2];
      TR4(vf, 0, vtr)
      #pragma unroll
      for (int dt = 0; dt < 8; dt++){
        if (dt < 7){
          unsigned pn = vtr + (unsigned)((dt + 1) * 32);
          TR4(vf, (dt + 1) & 1, pn)
          asm volatile("s_waitcnt lgkmcnt(4)" ::: "memory");
        } else {
          asm volatile("s_waitcnt lgkmcnt(0)" ::: "memory");
        }
        __builtin_amdgcn_sched_barrier(0);
        short8 v0 = cat8(vf[dt & 1][0][0], vf[dt & 1][0][1]);
        short8 v1 = cat8(vf[dt & 1][1][0], vf[dt & 1][1][1]);
        oA[dt] = __builtin_amdgcn_mfma_f32_16x16x32_bf16(pf[0], v0, oA[dt], 0, 0, 0);
        oA[dt] = __builtin_amdgcn_mfma_f32_16x16x32_bf16(pf[1], v1, oA[dt], 0, 0, 0);
      }
    }
  }
  #undef SMAX
  #undef TR4

  // ---- epilogues ----
  #pragma unroll
  for (int r = 0; r < 4; r++){ lA[r] = 1.0f / lA[r]; lB[r] = 1.0f / lB[r]; }
  #pragma unroll
  for (int dt = 0; dt < 8; dt++){
    #pragma unroll
    for (int r = 0; r < 4; r++){
      int qa = q0A + lg*4 + r;
      out[(size_t)(b * T + qa) * D + h * HD + dt*16 + lr] = f2bf(oA[dt][r] * lA[r]);
      int qb = q0B + lg*4 + r;
      out[(size_t)(b * T + qb) * D + h * HD + dt*16 + lr] = f2bf(oB[dt][r] * lB[r]);
    }
  }
}

extern "C" void kernel_launch(void* const* d_in, const int* in_sizes, int n_in,
                              void* d_out, int out_size, void* d_ws, size_t ws_size,
                              hipStream_t stream) {
  const float* x    = (const float*)d_in[0];   // [2,2048,2048]
  const float* wqkv = (const float*)d_in[1];   // [6144,2048]
  const float* wout = (const float*)d_in[2];   // [2048,2048]
  float* out = (float*)d_out;                  // [2,2048,2048] f32

  u16* ws    = (u16*)d_ws;
  u16* xb    = ws;                    //  8,388,608 elems
  u16* wqkvb = xb + 8388608;          // 12,582,912 elems
  u16* qkvb  = wqkvb + 12582912;      // 25,165,824 elems
  u16* attnb = xb;                    // alias: x dead after GEMM1
  u16* woutb = wqkvb;                 // alias: wqkv dead after GEMM1

  cvt_bf16<<<2048, 256, 0, stream>>>(x,    xb,    8388608 / 4);
  cvt_bf16<<<2048, 256, 0, stream>>>(wqkv, wqkvb, 12582912 / 4);

  // qkv = x @ Wqkv^T, split for exact grid quantization:
  //   cols 0..4095  : 256^2 8-phase, 16x16 = 256 blocks (1 clean round)
  //   cols 4096..6143: 128^2 m97,    32x16 = 512 blocks (2 clean rounds)
  gemm256<1><<<dim3(16, 16), 512, 0, stream>>>(xb, wqkvb, qkvb, 4096, 6144, 2048);
  gemm_bt<1><<<dim3(32, 16), 256, 0, stream>>>(xb, wqkvb + (size_t)4096 * 2048,
                                               qkvb + 4096, 4096, 6144, 2048);

  cvt_bf16<<<2048, 256, 0, stream>>>(wout, woutb, 4194304 / 4);

  // attention: [4096][2048] bf16  (512 blocks, fused dual-state tiles)
  attn_fwd<<<dim3(32, 16), 256, 0, stream>>>(qkvb, attnb);

  // y = attn @ Wout^T : [4096][2048] f32  (32x16 = 512 blocks, 2 rounds)
  gemm_bt<0><<<dim3(32, 16), 256, 0, stream>>>(attnb, woutb, out, 4096, 2048, 2048);
}

// Round 11
// 268.037 us; speedup vs baseline: 1.2639x; 1.2639x over previous
//
#include <hip/hip_runtime.h>

typedef short short8 __attribute__((ext_vector_type(8)));
typedef short short4v __attribute__((ext_vector_type(4)));
typedef float f32x4 __attribute__((ext_vector_type(4)));
typedef unsigned short u16;
typedef u16 ushort4v __attribute__((ext_vector_type(4)));

__device__ inline u16 f2bf(float f){
  unsigned int u = __builtin_bit_cast(unsigned int, f);
  u = (u + 0x7fffu + ((u >> 16) & 1u)) >> 16;
  return (u16)u;
}

__device__ inline short8 cat8(short4v a, short4v b){
  short8 r;
  r[0]=a[0]; r[1]=a[1]; r[2]=a[2]; r[3]=a[3];
  r[4]=b[0]; r[5]=b[1]; r[6]=b[2]; r[7]=b[3];
  return r;
}

// async global->LDS, 16B per lane. lds dest = wave-uniform base + lane*16.
__device__ inline void gload_lds16(const void* g, unsigned lds_addr){
  __builtin_amdgcn_global_load_lds((__attribute__((address_space(1))) void*)(uintptr_t)g,
                                   (__attribute__((address_space(3))) void*)(uintptr_t)lds_addr,
                                   16, 0, 0);
}

// ---------------- f32 -> bf16 convert (vectorized) ----------------
__global__ void cvt_bf16(const float* __restrict__ in, u16* __restrict__ out, int n4){
  int stride = gridDim.x * blockDim.x;
  for (int i = blockIdx.x * blockDim.x + threadIdx.x; i < n4; i += stride){
    float4 v = ((const float4*)in)[i];
    ushort4v r = { f2bf(v.x), f2bf(v.y), f2bf(v.z), f2bf(v.w) };
    ((ushort4v*)out)[i] = r;
  }
}

#define BARRIER() { __builtin_amdgcn_sched_barrier(0); __builtin_amdgcn_s_barrier(); __builtin_amdgcn_sched_barrier(0); }
#define VM4() asm volatile("s_waitcnt vmcnt(4)" ::: "memory");

// ================= 256x256 8-phase GEMM (~1092 TF/round, r6/r10) ==========
#define MFMA4(MO, AA, BB) { __builtin_amdgcn_s_setprio(1); \
  _Pragma("unroll") for (int m = 0; m < 4; m++) \
    _Pragma("unroll") for (int n = 0; n < 4; n++) \
      acc[(MO)+m][n] = __builtin_amdgcn_mfma_f32_16x16x32_bf16(AA[(MO)+m], BB[n], acc[(MO)+m][n], 0, 0, 0); \
  __builtin_amdgcn_s_setprio(0); }

#define PHASE4(ABASE, BBASE, ST1, ST2, ST3, ST4) { \
    const u16* Ab = (ABASE); const u16* Bb = (BBASE); \
    short8 a0[8], b0[4], a1[8], b1[4]; \
    _Pragma("unroll") for (int m = 0; m < 8; m++){ int row = wm*128 + m*16 + lr; int ph = lg ^ (row & 7); a0[m] = *(const short8*)&Ab[row*64 + ph*8]; } \
    _Pragma("unroll") for (int n = 0; n < 4; n++){ int row = wn*64 + n*16 + lr; int ph = lg ^ (row & 7); b0[n] = *(const short8*)&Bb[row*64 + ph*8]; } \
    ST1 BARRIER() MFMA4(0, a0, b0) BARRIER() \
    _Pragma("unroll") for (int m = 0; m < 8; m++){ int row = wm*128 + m*16 + lr; int ph = (4+lg) ^ (row & 7); a1[m] = *(const short8*)&Ab[row*64 + ph*8]; } \
    _Pragma("unroll") for (int n = 0; n < 4; n++){ int row = wn*64 + n*16 + lr; int ph = (4+lg) ^ (row & 7); b1[n] = *(const short8*)&Bb[row*64 + ph*8]; } \
    ST2 BARRIER() MFMA4(4, a0, b0) BARRIER() \
    ST3 BARRIER() MFMA4(0, a1, b1) BARRIER() \
    ST4 VM4() BARRIER() MFMA4(4, a1, b1) BARRIER() \
  }

template<int OUT_BF16>
__global__ __launch_bounds__(512, 2) void gemm256(const u16* __restrict__ A, const u16* __restrict__ B,
                                                  void* __restrict__ Cv, int M, int NS, int K){
  __shared__ u16 lds[2][32768];
  const int tid = threadIdx.x, wave = tid >> 6, lane = tid & 63;
  const int lr = lane & 15, lg = lane >> 4;
  const int wm = wave >> 2, wn = wave & 3;
  const long bm = blockIdx.x * 256L, bn = blockIdx.y * 256L;
  const int l3 = lane >> 3, l7 = lane & 7;

  const u16* asrc = A + (bm + wave*8 + l3) * (long)K + (l7 ^ l3) * 8;
  const u16* bsrc = B + (bn + wave*8 + l3) * (long)K + (l7 ^ l3) * 8;
  const unsigned ldsbase = (unsigned)(uintptr_t)&lds[0][0];
  const unsigned wdst = wave * 1024u;

#define STG_A(BUF,S,KOFF) gload_lds16(asrc + (size_t)(S)*64*K + (KOFF), ldsbase + (BUF)*65536u + wdst + (S)*8192u);
#define STG_B(BUF,S,KOFF) gload_lds16(bsrc + (size_t)(S)*64*K + (KOFF), ldsbase + (BUF)*65536u + 32768u + wdst + (S)*8192u);

  f32x4 acc[8][4] = {};
  const int nk = K >> 6;          // must be even

  #pragma unroll
  for (int s = 0; s < 4; s++){ STG_A(0, s, 0) }
  #pragma unroll
  for (int s = 0; s < 4; s++){ STG_B(0, s, 0) }
  #pragma unroll
  for (int s = 0; s < 4; s++){ STG_A(1, s, 64) }
  VM4()
  BARRIER()

  for (int i = 0; i < (nk >> 1); i++){
    const size_t kt1 = (size_t)((2*i + 1) << 6);
    const size_t kn0 = (size_t)(((2*i + 2) & (nk - 1)) << 6);
    const size_t kn1 = (size_t)(((2*i + 3) & (nk - 1)) << 6);
    PHASE4(&lds[0][0], &lds[0][16384],
           STG_B(1,0,kt1) STG_B(1,1,kt1),
           STG_B(1,2,kt1) STG_B(1,3,kt1),
           STG_A(0,0,kn0) STG_A(0,1,kn0),
           STG_A(0,2,kn0) STG_A(0,3,kn0))
    PHASE4(&lds[1][0], &lds[1][16384],
           STG_B(0,0,kn0) STG_B(0,1,kn0),
           STG_B(0,2,kn0) STG_B(0,3,kn0),
           STG_A(1,0,kn1) STG_A(1,1,kn1),
           STG_A(1,2,kn1) STG_A(1,3,kn1))
  }
#undef STG_A
#undef STG_B

  #pragma unroll
  for (int m = 0; m < 8; m++){
    #pragma unroll
    for (int n = 0; n < 4; n++){
      #pragma unroll
      for (int r = 0; r < 4; r++){
        long row = bm + wm*128 + m*16 + lg*4 + r;
        long col = bn + wn*64 + n*16 + lr;
        float v = acc[m][n][r];
        if (OUT_BF16) ((u16*)Cv)[row * (long)NS + col] = f2bf(v);
        else          ((float*)Cv)[row * (long)NS + col] = v;
      }
    }
  }
}

// ---------------- 128x128 m97 GEMM (862 TF; NS = output row stride) -------
template<int OUT_BF16>
__global__ __launch_bounds__(256) void gemm_bt(const u16* __restrict__ A, const u16* __restrict__ B,
                                               void* __restrict__ Cv, int M, int NS, int K){
  __shared__ u16 As[128 * 64];
  __shared__ u16 Bs[128 * 64];
  const int tid  = threadIdx.x;
  const int wave = tid >> 6, lane = tid & 63;
  const int lr = lane & 15, lg = lane >> 4;
  const int wm = wave >> 1, wn = wave & 1;
  const long bm = blockIdx.x * 128L, bn = blockIdx.y * 128L;
  const unsigned asb = (unsigned)(uintptr_t)As;
  const unsigned bsb = (unsigned)(uintptr_t)Bs;

  const int  srow = wave * 32 + (lane >> 3);
  const int  scol = ((lane & 7) ^ (lane >> 3)) * 8;
  const u16* aptr = A + (bm + srow) * (long)K + scol;
  const u16* bptr = B + (bn + srow) * (long)K + scol;
  const unsigned sdst = (unsigned)(wave * 4096);

  f32x4 acc[4][4] = {};
  for (int k0 = 0; k0 < K; k0 += 64){
    #pragma unroll
    for (int c = 0; c < 4; c++){
      gload_lds16(aptr + (size_t)(8 * c) * K + k0, asb + sdst + 1024u * c);
      gload_lds16(bptr + (size_t)(8 * c) * K + k0, bsb + sdst + 1024u * c);
    }
    __syncthreads();
    #pragma unroll
    for (int kk = 0; kk < 2; kk++){
      short8 af[4], bfr[4];
      #pragma unroll
      for (int m = 0; m < 4; m++){
        int row = wm * 64 + m * 16 + lr;
        int phys = (kk * 4 + lg) ^ (row & 7);
        af[m] = *(const short8*)&As[row * 64 + phys * 8];
      }
      #pragma unroll
      for (int n = 0; n < 4; n++){
        int row = wn * 64 + n * 16 + lr;
        int phys = (kk * 4 + lg) ^ (row & 7);
        bfr[n] = *(const short8*)&Bs[row * 64 + phys * 8];
      }
      #pragma unroll
      for (int m = 0; m < 4; m++)
        #pragma unroll
        for (int n = 0; n < 4; n++)
          acc[m][n] = __builtin_amdgcn_mfma_f32_16x16x32_bf16(af[m], bfr[n], acc[m][n], 0, 0, 0);
    }
    __syncthreads();
  }
  #pragma unroll
  for (int m = 0; m < 4; m++){
    #pragma unroll
    for (int n = 0; n < 4; n++){
      #pragma unroll
      for (int r = 0; r < 4; r++){
        long row = bm + wm*64 + m*16 + lg*4 + r;
        long col = bn + wn*64 + n*16 + lr;
        float v = acc[m][n][r];
        if (OUT_BF16) ((u16*)Cv)[row * (long)NS + col] = f2bf(v);
        else          ((float*)Cv)[row * (long)NS + col] = v;
      }
    }
  }
}

// ---------------- causal flash attention (r6 512-thread structure) --------
// 512 thr = 8 waves; Q-tile 128 (16 rows/wave); KV-tile 64. Paired q-tiles
// (15-pr heavy first, then pr) -> uniform work. log2-softmax + defer-max.
__global__ __launch_bounds__(512, 2) void attn_fwd(const u16* __restrict__ qkv, u16* __restrict__ out){
  const int T = 2048, D3 = 6144, D = 2048, HD = 128;
  const int bh = blockIdx.x;
  const int pr = blockIdx.y;            // 0..7
  const int b = bh >> 4, h = bh & 15;
  const int tid = threadIdx.x, wave = tid >> 6, lane = tid & 63;
  const int lr = lane & 15, lg = lane >> 4;

  __shared__ u16 Klds[64][136];
  __shared__ u16 Vlds[64][136];
  __shared__ u16 Plds[8][16][72];

  const size_t base = (size_t)b * T * D3;
  const unsigned vtr = (unsigned)(uintptr_t)&Vlds[(lane >> 4) * 8 + ((lane >> 2) & 3)][(lane & 3) * 4];

  const int srow = tid >> 4;
  const int scol = (tid & 15) * 8;
  const u16* kgp = qkv + base + (size_t)srow * D3 + D + h * HD + scol;
  const u16* vgp = kgp + D;

  const float scale2 = 0.12751971252971732f;  // 1/sqrt(128) * log2(e)
  const float THR = 11.5f;

  for (int half = 0; half < 2; half++){
    const int qt = half ? pr : (15 - pr);
    const int q0 = qt * 128;
    const int q0w = q0 + wave * 16;

    short8 qf[4];
    {
      const u16* qrow = qkv + base + (size_t)(q0w + lr) * D3 + h * HD;
      #pragma unroll
      for (int kk = 0; kk < 4; kk++)
        qf[kk] = *(const short8*)(qrow + kk*32 + lg*8);
    }

    f32x4 o[8] = {};
    float mrow[4], lrw[4];
    #pragma unroll
    for (int r = 0; r < 4; r++){ mrow[r] = -1e30f; lrw[r] = 0.f; }

    const int ntiles = (q0 + 128) >> 6;
    short8 kreg[2], vreg[2];
    #pragma unroll
    for (int c = 0; c < 2; c++){
      kreg[c] = *(const short8*)(kgp + (size_t)(32 * c) * D3);
      vreg[c] = *(const short8*)(vgp + (size_t)(32 * c) * D3);
    }

    for (int t = 0; t < ntiles; t++){
      const int k0 = t * 64;
      __syncthreads();
      #pragma unroll
      for (int c = 0; c < 2; c++){
        *(short8*)&Klds[srow + 32*c][scol] = kreg[c];
        *(short8*)&Vlds[srow + 32*c][scol] = vreg[c];
      }
      __syncthreads();
      if (t + 1 < ntiles){
        const u16* kn = kgp + (size_t)(k0 + 64) * D3;
        const u16* vn = vgp + (size_t)(k0 + 64) * D3;
        #pragma unroll
        for (int c = 0; c < 2; c++){
          kreg[c] = *(const short8*)(kn + (size_t)(32 * c) * D3);
          vreg[c] = *(const short8*)(vn + (size_t)(32 * c) * D3);
        }
      }

      if (k0 <= q0w + 15){
        // ---- S = Q K^T ----
        f32x4 s[4] = {};
        #pragma unroll
        for (int kh = 0; kh < 4; kh++){
          #pragma unroll
          for (int kk = 0; kk < 4; kk++){
            short8 kfrag = *(const short8*)&Klds[kh*16 + lr][kk*32 + lg*8];
            s[kh] = __builtin_amdgcn_mfma_f32_16x16x32_bf16(qf[kk], kfrag, s[kh], 0, 0, 0);
          }
        }
        const bool need_mask = (k0 + 63 > q0w);
        #pragma unroll
        for (int kh = 0; kh < 4; kh++){
          int key = k0 + kh*16 + lr;
          #pragma unroll
          for (int r = 0; r < 4; r++){
            float v = s[kh][r] * scale2;
            if (need_mask && key > q0w + lg*4 + r) v = -1e30f;
            s[kh][r] = v;
          }
        }
        // ---- log2-domain online softmax with defer-max ----
        float mx[4];
        #pragma unroll
        for (int r = 0; r < 4; r++){
          float m0 = fmaxf(fmaxf(s[0][r], s[1][r]), fmaxf(s[2][r], s[3][r]));
          #pragma unroll
          for (int msk = 8; msk >= 1; msk >>= 1)
            m0 = fmaxf(m0, __shfl_xor(m0, msk, 64));
          mx[r] = m0;
        }
        bool cnd = (mx[0] <= mrow[0] + THR) && (mx[1] <= mrow[1] + THR) &&
                   (mx[2] <= mrow[2] + THR) && (mx[3] <= mrow[3] + THR);
        if (__all(cnd)){
          #pragma unroll
          for (int r = 0; r < 4; r++){
            float p0 = exp2f(s[0][r] - mrow[r]);
            float p1 = exp2f(s[1][r] - mrow[r]);
            float p2 = exp2f(s[2][r] - mrow[r]);
            float p3 = exp2f(s[3][r] - mrow[r]);
            s[0][r] = p0; s[1][r] = p1; s[2][r] = p2; s[3][r] = p3;
            float rs = (p0 + p1) + (p2 + p3);
            #pragma unroll
            for (int msk = 8; msk >= 1; msk >>= 1)
              rs += __shfl_xor(rs, msk, 64);
            lrw[r] += rs;
          }
        } else {
          float fs[4];
          #pragma unroll
          for (int r = 0; r < 4; r++){
            float mnew = fmaxf(mrow[r], mx[r]);
            float f = exp2f(mrow[r] - mnew);
            float p0 = exp2f(s[0][r] - mnew);
            float p1 = exp2f(s[1][r] - mnew);
            float p2 = exp2f(s[2][r] - mnew);
            float p3 = exp2f(s[3][r] - mnew);
            s[0][r] = p0; s[1][r] = p1; s[2][r] = p2; s[3][r] = p3;
            float rs = (p0 + p1) + (p2 + p3);
            #pragma unroll
            for (int msk = 8; msk >= 1; msk >>= 1)
              rs += __shfl_xor(rs, msk, 64);
            lrw[r] = lrw[r] * f + rs;
            mrow[r] = mnew;
            fs[r] = f;
          }
          #pragma unroll
          for (int dt = 0; dt < 8; dt++)
            #pragma unroll
            for (int r = 0; r < 4; r++)
              o[dt][r] *= fs[r];
        }
        // ---- P -> LDS (bf16) ----
        #pragma unroll
        for (int kh = 0; kh < 4; kh++)
          #pragma unroll
          for (int r = 0; r < 4; r++)
            Plds[wave][lg*4 + r][kh*16 + lr] = f2bf(s[kh][r]);
        asm volatile("s_waitcnt lgkmcnt(0)" ::: "memory");
        __builtin_amdgcn_sched_barrier(0);
        short8 pf[2];
        #pragma unroll
        for (int kp2 = 0; kp2 < 2; kp2++)
          pf[kp2] = *(const short8*)&Plds[wave][lr][kp2*32 + lg*8];
        asm volatile("s_waitcnt lgkmcnt(0)" ::: "memory");
        __builtin_amdgcn_sched_barrier(0);

        // ---- PV with pipelined hardware-transpose V reads ----
        short4v vf[2][2][2];
        #define TR4(BUF, PTR) \
          asm volatile("ds_read_b64_tr_b16 %0, %1"             : "=v"(vf[BUF][0][0]) : "v"(PTR)); \
          asm volatile("ds_read_b64_tr_b16 %0, %1 offset:1088" : "=v"(vf[BUF][0][1]) : "v"(PTR)); \
          asm volatile("ds_read_b64_tr_b16 %0, %1 offset:8704" : "=v"(vf[BUF][1][0]) : "v"(PTR)); \
          asm volatile("ds_read_b64_tr_b16 %0, %1 offset:9792" : "=v"(vf[BUF][1][1]) : "v"(PTR));
        TR4(0, vtr)
        #pragma unroll
        for (int dt = 0; dt < 8; dt++){
          if (dt < 7){
            unsigned pn = vtr + (unsigned)((dt + 1) * 32);
            TR4((dt + 1) & 1, pn)
            asm volatile("s_waitcnt lgkmcnt(4)" ::: "memory");
          } else {
            asm volatile("s_waitcnt lgkmcnt(0)" ::: "memory");
          }
          __builtin_amdgcn_sched_barrier(0);
          short8 v0 = cat8(vf[dt & 1][0][0], vf[dt & 1][0][1]);
          short8 v1 = cat8(vf[dt & 1][1][0], vf[dt & 1][1][1]);
          o[dt] = __builtin_amdgcn_mfma_f32_16x16x32_bf16(pf[0], v0, o[dt], 0, 0, 0);
          o[dt] = __builtin_amdgcn_mfma_f32_16x16x32_bf16(pf[1], v1, o[dt], 0, 0, 0);
        }
        #undef TR4
      }
    }
    // ---- epilogue for this half ----
    float rl[4];
    #pragma unroll
    for (int r = 0; r < 4; r++) rl[r] = 1.0f / lrw[r];
    #pragma unroll
    for (int dt = 0; dt < 8; dt++){
      #pragma unroll
      for (int r = 0; r < 4; r++){
        float v = o[dt][r] * rl[r];
        int qa = q0w + lg*4 + r;
        out[(size_t)(b * T + qa) * D + h * HD + dt*16 + lr] = f2bf(v);
      }
    }
  }
}

extern "C" void kernel_launch(void* const* d_in, const int* in_sizes, int n_in,
                              void* d_out, int out_size, void* d_ws, size_t ws_size,
                              hipStream_t stream) {
  const float* x    = (const float*)d_in[0];   // [2,2048,2048]
  const float* wqkv = (const float*)d_in[1];   // [6144,2048]
  const float* wout = (const float*)d_in[2];   // [2048,2048]
  float* out = (float*)d_out;                  // [2,2048,2048] f32

  u16* ws    = (u16*)d_ws;
  u16* xb    = ws;                    //  8,388,608 elems
  u16* wqkvb = xb + 8388608;          // 12,582,912 elems
  u16* qkvb  = wqkvb + 12582912;      // 25,165,824 elems
  u16* attnb = xb;                    // alias: x dead after GEMM1
  u16* woutb = wqkvb;                 // alias: wqkv dead after GEMM1

  cvt_bf16<<<2048, 256, 0, stream>>>(x,    xb,    8388608 / 4);
  cvt_bf16<<<2048, 256, 0, stream>>>(wqkv, wqkvb, 12582912 / 4);

  // qkv = x @ Wqkv^T, split for exact grid quantization:
  //   cols 0..4095  : 256^2 8-phase, 16x16 = 256 blocks (1 clean round)
  //   cols 4096..6143: 128^2 m97,    32x16 = 512 blocks (2 clean rounds)
  gemm256<1><<<dim3(16, 16), 512, 0, stream>>>(xb, wqkvb, qkvb, 4096, 6144, 2048);
  gemm_bt<1><<<dim3(32, 16), 256, 0, stream>>>(xb, wqkvb + (size_t)4096 * 2048,
                                               qkvb + 4096, 4096, 6144, 2048);

  cvt_bf16<<<2048, 256, 0, stream>>>(wout, woutb, 4194304 / 4);

  // attention: [4096][2048] bf16  (r6 512-thread structure, 32x8 grid)
  attn_fwd<<<dim3(32, 8), 512, 0, stream>>>(qkvb, attnb);

  // y = attn @ Wout^T : [4096][2048] f32  (32x16 = 512 blocks, 2 rounds)
  gemm_bt<0><<<dim3(32, 16), 256, 0, stream>>>(attnb, woutb, out, 4096, 2048, 2048);
}